// Round 2
// baseline (95.514 us; speedup 1.0000x reference)
//
#include <hip/hip_runtime.h>
#include <math.h>

#define SIDELEN 128
#define KCOEF   5
#define TILE    16          // 16x16 px tiles -> 8x8 tiles per batch
#define NTILE   8           // tiles per axis
#define SPLITS  16          // work-split blocks per tile (bounds hot-tile latency)
#define CHUNK   64          // candidates staged to LDS per iteration

__device__ __forceinline__ float fexp2(float x) {
    return __builtin_amdgcn_exp2f(x);
}
__device__ __forceinline__ float frcp(float x) {
    return __builtin_amdgcn_rcpf(x);
}

// floor(x/16) for x possibly negative (|x| < 4096)
__device__ __forceinline__ int fdiv16(int x) { return ((x + 4096) >> 4) - 256; }

// ---------------------------------------------------------------------------
// Kernel 1: per (b,atom) precompute 12-float record {u, v, (c2,w)x5} and bin
// the atom index into every tile its 16x16 patch overlaps (<=4 tiles).
//   u,v = coord + 64 (pixel-index space); patch rows [floor(u)-7, floor(u)+8]
//   c2  = -4*pi^2*log2(e)/b   (exponent coeff for exp2)
//   w   =  4*pi*a/b
// ---------------------------------------------------------------------------
__global__ __launch_bounds__(256) void prep_bin(
    const float* __restrict__ coords,  // (B, A, 3)
    const float* __restrict__ ffa,     // (A, K)
    const float* __restrict__ ffb,     // (A, K)
    float* __restrict__ recs,          // (B*A, 12)
    int*   __restrict__ cnt,           // (B*64), pre-zeroed
    int*   __restrict__ list,          // (B*64, A)
    int B, int A)
{
    const int t = blockIdx.x * 256 + threadIdx.x;
    if (t >= B * A) return;
    const int b = t / A;
    const int a = t - b * A;

    const float x = coords[(size_t)t * 3 + 0];
    const float y = coords[(size_t)t * 3 + 1];
    const float u = x + 64.0f;
    const float v = y + 64.0f;

    float* r = recs + (size_t)t * 12;
    r[0] = u;
    r[1] = v;
#pragma unroll
    for (int k = 0; k < KCOEF; ++k) {
        const float rb = frcp(ffb[a * KCOEF + k]);
        r[2 + 2 * k] = -56.95531725f * rb;                    // 4*pi^2*log2(e)/b
        r[3 + 2 * k] = 12.56637061f * ffa[a * KCOEF + k] * rb; // 4*pi*a/b
    }

    // Patch row/col extents in pixel-index space
    const int r0 = (int)floorf(u) - 7;
    const int c0 = (int)floorf(v) - 7;
    int tr0 = fdiv16(r0), tr1 = fdiv16(r0 + TILE - 1);
    int tc0 = fdiv16(c0), tc1 = fdiv16(c0 + TILE - 1);
    if (tr0 < 0) tr0 = 0;  if (tr1 > NTILE - 1) tr1 = NTILE - 1;
    if (tc0 < 0) tc0 = 0;  if (tc1 > NTILE - 1) tc1 = NTILE - 1;

    for (int tr = tr0; tr <= tr1; ++tr)
        for (int tc = tc0; tc <= tc1; ++tc) {
            const int tile = b * (NTILE * NTILE) + tr * NTILE + tc;
            const int pos  = atomicAdd(cnt + tile, 1);
            list[(size_t)tile * A + pos] = a;
        }
}

// ---------------------------------------------------------------------------
// Kernel 2: gather. One block = (tile, split). 256 threads = 256 tile pixels.
// Candidate atoms LDS-staged in chunks; every lane evaluates every candidate
// (broadcast LDS reads). One atomicAdd per pixel per block (16/address max).
// ---------------------------------------------------------------------------
__global__ __launch_bounds__(256) void gather(
    const float* __restrict__ recs,    // (B*A, 12)
    const int*   __restrict__ cnt,     // (B*64)
    const int*   __restrict__ list,    // (B*64, A)
    float* __restrict__ out,           // (B, 128, 128), pre-zeroed
    int A)
{
    const int tile = blockIdx.x;           // 0..63
    const int b    = blockIdx.y;
    const int z    = blockIdx.z;           // split slice
    const int tid  = threadIdx.x;

    const int tr = tile >> 3, tc = tile & 7;
    const int r = tr * TILE + (tid >> 4);
    const int c = tc * TILE + (tid & 15);
    const float pr = (float)r;
    const float pc = (float)c;

    const int gt = b * (NTILE * NTILE) + tile;
    const int n  = cnt[gt];
    const int* tl = list + (size_t)gt * A;

    __shared__ int   idx_sh[CHUNK];
    __shared__ float rec_sh[CHUNK][12];   // rows are 48 B -> float4-aligned

    float acc = 0.0f;

    for (int base = z * CHUNK; base < n; base += SPLITS * CHUNK) {
        const int m = min(CHUNK, n - base);

        if (tid < m) idx_sh[tid] = tl[base + tid];
        __syncthreads();

        // stage m records (12 floats each) as float4 triplets
        {
            const int ci = tid / 3;        // candidate
            const int q  = tid - ci * 3;   // which float4 of the record
            if (ci < m) {
                const float4* src = (const float4*)recs;
                ((float4*)&rec_sh[ci][0])[q] =
                    src[((size_t)(b * A + idx_sh[ci])) * 3 + q];
            }
        }
        __syncthreads();

        for (int i = 0; i < m; ++i) {
            const float u  = rec_sh[i][0];
            const float v  = rec_sh[i][1];
            const float dx = pr - u;
            const float dy = pc - v;
            const float d2 = fmaf(dx, dx, dy * dy);
#pragma unroll
            for (int k = 0; k < KCOEF; ++k) {
                const float c2 = rec_sh[i][2 + 2 * k];
                const float w  = rec_sh[i][3 + 2 * k];
                acc = fmaf(w, fexp2(c2 * d2), acc);
            }
        }
        __syncthreads();   // protect LDS before next chunk's staging
    }

    if (acc != 0.0f)
        atomicAdd(out + ((size_t)b * (SIDELEN * SIDELEN) + r * SIDELEN + c), acc);
}

extern "C" void kernel_launch(void* const* d_in, const int* in_sizes, int n_in,
                              void* d_out, int out_size, void* d_ws, size_t ws_size,
                              hipStream_t stream) {
    const float* coords = (const float*)d_in[0];   // (B, A, 3)
    const float* ffa    = (const float*)d_in[1];   // (A, K)
    const float* ffb    = (const float*)d_in[2];   // (A, K)
    float* out = (float*)d_out;

    const int A = in_sizes[1] / KCOEF;
    const int B = in_sizes[0] / (3 * A);
    const int NT = NTILE * NTILE;                  // tiles per batch

    // workspace layout
    char* ws = (char*)d_ws;
    float* recs = (float*)ws;                                   // B*A*12 floats
    size_t rec_bytes = (size_t)B * A * 12 * sizeof(float);
    int* cnt = (int*)(ws + rec_bytes);                          // B*64 ints
    size_t cnt_bytes = (size_t)B * NT * sizeof(int);
    int* list = (int*)(ws + rec_bytes + cnt_bytes);             // B*64*A ints

    // zero accumulator + tile counters (ws/d_out are poisoned 0xAA each call)
    hipMemsetAsync(cnt, 0, cnt_bytes, stream);
    hipMemsetAsync(d_out, 0, (size_t)out_size * sizeof(float), stream);

    prep_bin<<<dim3((B * A + 255) / 256), dim3(256), 0, stream>>>(
        coords, ffa, ffb, recs, cnt, list, B, A);

    gather<<<dim3(NT, B, SPLITS), dim3(256), 0, stream>>>(
        recs, cnt, list, out, A);
}